// Round 2
// baseline (1050.789 us; speedup 1.0000x reference)
//
#include <hip/hip_runtime.h>
#include <hip/hip_bf16.h>

// ---------------------------------------------------------------------------
// StreamingQwenMoE round 2: correctness + small-workspace (~67 MB).
//   - fp8 block-scale dequant FUSED into GEMM B staging (f32*scale -> f16 LDS)
//   - combine FUSED into down-GEMM epilogues:
//       routed: f32 hardware atomics (w_slot * val) into d_out
//       shared: plain out += shg[t] * val (last kernel, unique rows)
//   - d_out zero-initialized every call (harness poisons once, never restores)
// Round-1 verified pieces kept: MFMA fragment layout, router top-8/renorm,
// SwiGLU epilogue, gather dispatch.
// Debts (future rounds): LDS bank-conflict swizzle, deeper pipeline, BM=256.
// ---------------------------------------------------------------------------

#define TT   2048   // tokens
#define DD   2048   // hidden
#define DFF  768    // routed intermediate
#define DSH  2048   // shared intermediate
#define EE   32     // experts
#define KTOP 8
#define CAP  1024

typedef _Float16 half8  __attribute__((ext_vector_type(8)));
typedef _Float16 half4v __attribute__((ext_vector_type(4)));
typedef float    f32x4  __attribute__((ext_vector_type(4)));

// ---------------- init: zero per-expert counters + slot->token map ----------
__global__ __launch_bounds__(256) void k_init(int* __restrict__ cnt,
                                              int* __restrict__ slot_tok) {
  int i = blockIdx.x * 256 + threadIdx.x;
  if (i < EE * CAP) slot_tok[i] = 0;   // unfilled slots -> token 0 (rows masked)
  if (i < EE) cnt[i] = 0;
}

// ---------------- zero d_out (poisoned by harness, we accumulate into it) ---
__global__ __launch_bounds__(256) void k_zero(float* __restrict__ out) {
  int i = blockIdx.x * 256 + threadIdx.x;
  ((float4*)out)[i] = (float4){0.f, 0.f, 0.f, 0.f};
}

// ---------------- f32 -> f16 cast (exact multiple of 1024 elems) ------------
__global__ __launch_bounds__(256) void k_cast(const float* __restrict__ in,
                                              _Float16* __restrict__ out) {
  int i = blockIdx.x * 256 + threadIdx.x;
  float4 v = ((const float4*)in)[i];
  half4v h = { (_Float16)v.x, (_Float16)v.y, (_Float16)v.z, (_Float16)v.w };
  ((half4v*)out)[i] = h;
}

// ---------------- router: logits, top8, renorm, dispatch --------------------
__global__ __launch_bounds__(64) void k_router(
    const float* __restrict__ x, const float* __restrict__ rw,
    const float* __restrict__ wshg,
    float* __restrict__ shg, int* __restrict__ cnt,
    int* __restrict__ slot_tok, float* __restrict__ slot_w) {
  int t = blockIdx.x;
  int lane = threadIdx.x;
  const float* xr = x + (size_t)t * DD;
  float xv[32];
#pragma unroll
  for (int j = 0; j < 32; ++j) xv[j] = xr[lane + j * 64];

  __shared__ float lg[EE];
  for (int e = 0; e < EE; ++e) {
    const float* we = rw + (size_t)e * DD;
    float s = 0.f;
#pragma unroll
    for (int j = 0; j < 32; ++j) s += xv[j] * we[lane + j * 64];
#pragma unroll
    for (int off = 32; off > 0; off >>= 1) s += __shfl_down(s, off);
    if (lane == 0) lg[e] = s;
  }
  {  // shared-expert sigmoid gate
    float s = 0.f;
#pragma unroll
    for (int j = 0; j < 32; ++j) s += xv[j] * wshg[lane + j * 64];
#pragma unroll
    for (int off = 32; off > 0; off >>= 1) s += __shfl_down(s, off);
    if (lane == 0) shg[t] = 1.f / (1.f + expf(-s));
  }
  if (lane == 0) {
    unsigned used = 0;
    int sel[KTOP];
    float val[KTOP];
    for (int k = 0; k < KTOP; ++k) {     // top-8, ties -> lower index
      float bv = -1e30f; int bi = 0;
      for (int e = 0; e < EE; ++e)
        if (!((used >> e) & 1) && lg[e] > bv) { bv = lg[e]; bi = e; }
      used |= (1u << bi);
      sel[k] = bi; val[k] = bv;
    }
    float mx = val[0], sum = 0.f;
    for (int k = 0; k < KTOP; ++k) { val[k] = expf(val[k] - mx); sum += val[k]; }
    float inv = 1.f / sum;
    for (int k = 0; k < KTOP; ++k) {
      int e = sel[k];
      int pos = atomicAdd(&cnt[e], 1);
      if (pos < CAP) {
        slot_tok[e * CAP + pos] = t;
        slot_w[e * CAP + pos] = val[k] * inv;
      }
    }
  }
}

// ---------------- grouped GEMM: C = A (rows x K, f16) * B (N x K, f32)^T ----
// DUAL: two B operands (gate/up) + SwiGLU -> f16 OutH
// GATHER: A rows indirected through slot_tok
// DEQ: B is fp8-sim f32 with 128x128 block scales (dequant fused at staging)
// EPI: 0 = write f16 OutH; 1 = atomic scatter w_slot*val into OutF (f32);
//      2 = OutF[row] += shg[row]*val (shared-down, runs last)
template<bool DUAL, bool GATHER, bool DEQ, int EPI>
__global__ __launch_bounds__(256) void k_gemm(
    const _Float16* __restrict__ A,
    const float* __restrict__ B0f, const float* __restrict__ B1f,
    const float* __restrict__ S0, const float* __restrict__ S1,
    int sCols, int sStrideE,
    _Float16* __restrict__ OutH, float* __restrict__ OutF,
    const float* __restrict__ shg,
    int K, int ldA, int ldOut,
    long long strideAE, long long strideBE, long long strideOE,
    const int* __restrict__ cnt, int rowsConst,
    const int* __restrict__ slot_tok, const float* __restrict__ slot_w) {
  constexpr int BM = 128, BK = 64;
  constexpr int NF = DUAL ? 2 : 4;     // 16-col fragments per wave per operand
  constexpr int BN = DUAL ? 64 : 128;  // per-operand N tile
  constexpr int BCH = DUAL ? 4 : 8;    // float4 chunks per thread per operand

  const int e = blockIdx.z;
  int rows = cnt ? (cnt[e] > CAP ? CAP : cnt[e]) : rowsConst;
  const int rowBase = blockIdx.y * BM;
  if (rowBase >= rows) return;
  const int nBase = blockIdx.x * BN;

  const int tid = threadIdx.x;
  const int lane = tid & 63;
  const int wave = tid >> 6;
  const int wr = wave >> 1;   // 2x2 wave grid; 64 rows per wave-row
  const int wc = wave & 1;

  __shared__ _Float16 sA[BM * BK];     // 16 KB
  __shared__ _Float16 sB[128 * BK];    // 16 KB (dual: [gate 64xBK][up 64xBK])

  const _Float16* Ae = A + (GATHER ? 0 : (long long)e * strideAE);
  const float* B0e = B0f + (long long)e * strideBE;
  const float* B1e = DUAL ? (B1f + (long long)e * strideBE) : nullptr;
  const float* S0e = DEQ ? (S0 + (long long)e * sStrideE) : nullptr;
  const float* S1e = (DEQ && DUAL) ? (S1 + (long long)e * sStrideE) : nullptr;

  // A staging: 4 x 16B f16 chunks per thread (128 rows x 64 cols)
  long long aOff[4];
#pragma unroll
  for (int i = 0; i < 4; ++i) {
    int c = tid + i * 256;
    int r = c >> 3;
    int grow = rowBase + r;
    int src = GATHER ? slot_tok[e * CAP + grow] : grow;
    aOff[i] = (long long)src * ldA + (c & 7) * 8;
  }
  // B staging: BCH x float4 chunks per thread per operand (BN rows x 64 cols)
  int bRow[BCH], bCol0[BCH], sIdx[BCH];
  long long bOff[BCH];
#pragma unroll
  for (int i = 0; i < BCH; ++i) {
    int c = tid + i * 256;
    bRow[i] = c >> 4;                  // [0, BN)
    bCol0[i] = (c & 15) * 4;           // [0, 64) step 4
    bOff[i] = (long long)(nBase + bRow[i]) * K + bCol0[i];
    sIdx[i] = DEQ ? ((nBase + bRow[i]) >> 7) * sCols : 0;
  }

  f32x4 accG[4][NF];
  f32x4 accU[DUAL ? 4 : 1][NF];
#pragma unroll
  for (int m = 0; m < 4; ++m)
#pragma unroll
    for (int n = 0; n < NF; ++n) {
      accG[m][n] = (f32x4){0.f, 0.f, 0.f, 0.f};
      if constexpr (DUAL) accU[m][n] = (f32x4){0.f, 0.f, 0.f, 0.f};
    }

  uint4 ra[4];
  float4 rb0[BCH], rb1[BCH];
  float sc0[BCH], sc1[BCH];
  const int KT = K / BK;

  auto loadTile = [&](int kt) {
    const int ko = kt * BK;
    const int sk = kt >> 1;            // 128-wide scale block along K
#pragma unroll
    for (int i = 0; i < 4; ++i) ra[i] = *(const uint4*)(Ae + aOff[i] + ko);
#pragma unroll
    for (int i = 0; i < BCH; ++i) {
      rb0[i] = *(const float4*)(B0e + bOff[i] + ko);
      if constexpr (DEQ) sc0[i] = S0e[sIdx[i] + sk];
    }
    if constexpr (DUAL) {
#pragma unroll
      for (int i = 0; i < BCH; ++i) {
        rb1[i] = *(const float4*)(B1e + bOff[i] + ko);
        if constexpr (DEQ) sc1[i] = S1e[sIdx[i] + sk];
      }
    }
  };

  loadTile(0);

  for (int kt = 0; kt < KT; ++kt) {
    __syncthreads();   // previous iteration done reading LDS
#pragma unroll
    for (int i = 0; i < 4; ++i) *(uint4*)&sA[(tid + i * 256) * 8] = ra[i];
#pragma unroll
    for (int i = 0; i < BCH; ++i) {
      float s = DEQ ? sc0[i] : 1.f;
      half4v h = { (_Float16)(rb0[i].x * s), (_Float16)(rb0[i].y * s),
                   (_Float16)(rb0[i].z * s), (_Float16)(rb0[i].w * s) };
      *(half4v*)&sB[bRow[i] * BK + bCol0[i]] = h;
    }
    if constexpr (DUAL) {
#pragma unroll
      for (int i = 0; i < BCH; ++i) {
        float s = DEQ ? sc1[i] : 1.f;
        half4v h = { (_Float16)(rb1[i].x * s), (_Float16)(rb1[i].y * s),
                     (_Float16)(rb1[i].z * s), (_Float16)(rb1[i].w * s) };
        *(half4v*)&sB[64 * BK + bRow[i] * BK + bCol0[i]] = h;
      }
    }
    __syncthreads();   // LDS ready

    if (kt + 1 < KT) loadTile(kt + 1);  // overlap next-tile loads with MFMA

#pragma unroll
    for (int kk = 0; kk < 2; ++kk) {
      const int koff = kk * 32 + (lane >> 4) * 8;
      half8 a[4];
#pragma unroll
      for (int m = 0; m < 4; ++m)
        a[m] = *(const half8*)&sA[(wr * 64 + m * 16 + (lane & 15)) * BK + koff];
      if constexpr (DUAL) {
        half8 bg[2], bu[2];
#pragma unroll
        for (int n = 0; n < 2; ++n) {
          int rn = wc * 32 + n * 16 + (lane & 15);
          bg[n] = *(const half8*)&sB[rn * BK + koff];
          bu[n] = *(const half8*)&sB[64 * BK + rn * BK + koff];
        }
#pragma unroll
        for (int m = 0; m < 4; ++m)
#pragma unroll
          for (int n = 0; n < 2; ++n) {
            accG[m][n] = __builtin_amdgcn_mfma_f32_16x16x32_f16(a[m], bg[n], accG[m][n], 0, 0, 0);
            accU[m][n] = __builtin_amdgcn_mfma_f32_16x16x32_f16(a[m], bu[n], accU[m][n], 0, 0, 0);
          }
      } else {
        half8 b[4];
#pragma unroll
        for (int n = 0; n < 4; ++n)
          b[n] = *(const half8*)&sB[(wc * 64 + n * 16 + (lane & 15)) * BK + koff];
#pragma unroll
        for (int m = 0; m < 4; ++m)
#pragma unroll
          for (int n = 0; n < 4; ++n)
            accG[m][n] = __builtin_amdgcn_mfma_f32_16x16x32_f16(a[m], b[n], accG[m][n], 0, 0, 0);
      }
    }
  }

  // epilogue; C/D layout: col = lane&15, row = (lane>>4)*4 + i  (verified r1)
#pragma unroll
  for (int m = 0; m < 4; ++m) {
#pragma unroll
    for (int i = 0; i < 4; ++i) {
      int row = rowBase + wr * 64 + m * 16 + (lane >> 4) * 4 + i;
      if (row < rows) {
        if constexpr (EPI == 1) {       // routed scatter: out[tok] += w*val
          int tok = slot_tok[e * CAP + row];
          float w = slot_w[e * CAP + row];
#pragma unroll
          for (int n = 0; n < NF; ++n) {
            int col = nBase + wc * 64 + n * 16 + (lane & 15);
            unsafeAtomicAdd(&OutF[(long long)tok * DD + col],
                            w * accG[m][n][i]);
          }
        } else if constexpr (EPI == 2) {  // shared: out[row] += shg*val
          float g = shg[row];
#pragma unroll
          for (int n = 0; n < NF; ++n) {
            int col = nBase + wc * 64 + n * 16 + (lane & 15);
            long long o = (long long)row * DD + col;
            OutF[o] += g * accG[m][n][i];
          }
        } else {                          // f16 intermediate (SwiGLU if DUAL)
          long long outBase = (long long)e * strideOE;
#pragma unroll
          for (int n = 0; n < NF; ++n) {
            int col = nBase + (DUAL ? wc * 32 : wc * 64) + n * 16 + (lane & 15);
            long long o = outBase + (long long)row * ldOut + col;
            if constexpr (DUAL) {
              float gv = accG[m][n][i];
              float uv = accU[m][n][i];
              OutH[o] = (_Float16)((gv / (1.f + __expf(-gv))) * uv);
            } else {
              OutH[o] = (_Float16)accG[m][n][i];
            }
          }
        }
      }
    }
  }
}

// ---------------------------------------------------------------------------
extern "C" void kernel_launch(void* const* d_in, const int* in_sizes, int n_in,
                              void* d_out, int out_size, void* d_ws, size_t ws_size,
                              hipStream_t stream) {
  (void)in_sizes; (void)n_in; (void)out_size; (void)ws_size;
  const float* x    = (const float*)d_in[0];
  const float* rw   = (const float*)d_in[1];
  const float* wg   = (const float*)d_in[2];
  const float* sg   = (const float*)d_in[3];
  const float* wu   = (const float*)d_in[4];
  const float* su   = (const float*)d_in[5];
  const float* wd   = (const float*)d_in[6];
  const float* sd   = (const float*)d_in[7];
  const float* wsg  = (const float*)d_in[8];
  const float* wsu  = (const float*)d_in[9];
  const float* wsd  = (const float*)d_in[10];
  const float* wshg = (const float*)d_in[11];
  float* out = (float*)d_out;

  // workspace layout (~67.4 MB total)
  char* p = (char*)d_ws;
  auto alloc = [&](size_t bytes) {
    char* r = p;
    p += (bytes + 255) & ~(size_t)255;
    return r;
  };
  _Float16* x_h = (_Float16*)alloc((size_t)TT * DD * 2);         //  8.4 MB
  _Float16* H   = (_Float16*)alloc((size_t)EE * CAP * DFF * 2);  // 50.3 MB
  _Float16* Hsh = (_Float16*)alloc((size_t)TT * DSH * 2);        //  8.4 MB
  float* shg    = (float*)alloc((size_t)TT * 4);
  int* cnt      = (int*)alloc((size_t)EE * 4);
  int* slot_tok = (int*)alloc((size_t)EE * CAP * 4);
  float* slot_w = (float*)alloc((size_t)EE * CAP * 4);

  k_init<<<(EE * CAP + 255) / 256, 256, 0, stream>>>(cnt, slot_tok);
  k_zero<<<(TT * DD / 4) / 256, 256, 0, stream>>>(out);
  k_cast<<<(TT * DD / 4) / 256, 256, 0, stream>>>(x, x_h);
  k_router<<<TT, 64, 0, stream>>>(x, rw, wshg, shg, cnt, slot_tok, slot_w);

  // routed gate+up (gather A rows, fused dequant + SwiGLU): H[e, slot, DFF]
  k_gemm<true, true, true, 0><<<dim3(DFF / 64, CAP / 128, EE), 256, 0, stream>>>(
      x_h, wg, wu, sg, su, /*sCols=*/DD / 128, /*sStrideE=*/(DFF / 128) * (DD / 128),
      H, nullptr, nullptr,
      /*K=*/DD, /*ldA=*/DD, /*ldOut=*/DFF,
      0LL, (long long)DFF * DD, (long long)CAP * DFF,
      cnt, 0, slot_tok, nullptr);

  // routed down (fused dequant) + weighted atomic scatter into out
  k_gemm<false, false, true, 1><<<dim3(DD / 128, CAP / 128, EE), 256, 0, stream>>>(
      H, wd, wd, sd, sd, /*sCols=*/DFF / 128, /*sStrideE=*/(DD / 128) * (DFF / 128),
      nullptr, out, nullptr,
      /*K=*/DFF, /*ldA=*/DFF, /*ldOut=*/DD,
      (long long)CAP * DFF, (long long)DD * DFF, 0LL,
      cnt, 0, slot_tok, slot_w);

  // shared gate+up (SwiGLU): Hsh[T, DSH]
  k_gemm<true, false, false, 0><<<dim3(DSH / 64, TT / 128, 1), 256, 0, stream>>>(
      x_h, wsg, wsu, nullptr, nullptr, 0, 0,
      Hsh, nullptr, nullptr,
      /*K=*/DD, /*ldA=*/DD, /*ldOut=*/DSH,
      0LL, 0LL, 0LL,
      nullptr, TT, nullptr, nullptr);

  // shared down: out[t] += shg[t] * (Hsh[t] . wsd[n])   (runs last, unique rows)
  k_gemm<false, false, false, 2><<<dim3(DD / 128, TT / 128, 1), 256, 0, stream>>>(
      Hsh, wsd, wsd, nullptr, nullptr, 0, 0,
      nullptr, out, shg,
      /*K=*/DSH, /*ldA=*/DSH, /*ldOut=*/DD,
      0LL, 0LL, 0LL,
      nullptr, TT, nullptr, nullptr);
}

// Round 3
// 708.582 us; speedup vs baseline: 1.4829x; 1.4829x over previous
//
#include <hip/hip_runtime.h>
#include <hip/hip_bf16.h>

// ---------------------------------------------------------------------------
// StreamingQwenMoE round 3: attack the measured bottlenecks of round 2:
//   (1) 16-way LDS bank conflicts (SQ_LDS_BANK_CONFLICT=4.2e7) -> T2 XOR swizzle
//       byte ^= (row&7)<<4 ; sA swizzled via pre-swizzled GLOBAL source since
//       global_load_lds writes linearly (both-sides-or-neither rule).
//   (2) vmcnt(0) drain at every __syncthreads -> raw s_barrier + counted
//       s_waitcnt vmcnt(12) (one tile = 4 A-DMA + 8 B-loads stays in flight).
//       sA triple-buffered (2 DMA in flight + 1 being read), sB double.
//   (3) B-panel L2 misses across M-blocks -> bijective XCD swizzle: all
//       m-blocks of one (n,e) pair map to the same XCD, adjacent dispatch.
// Epilogues / router / dispatch math unchanged (verified rounds 1-2).
// ---------------------------------------------------------------------------

#define TT   2048
#define DD   2048
#define DFF  768
#define DSH  2048
#define EE   32
#define KTOP 8
#define CAP  1024

typedef _Float16 half8  __attribute__((ext_vector_type(8)));
typedef _Float16 half4v __attribute__((ext_vector_type(4)));
typedef float    f32x4  __attribute__((ext_vector_type(4)));

// ---------------- init: zero per-expert counters + slot->token map ----------
__global__ __launch_bounds__(256) void k_init(int* __restrict__ cnt,
                                              int* __restrict__ slot_tok) {
  int i = blockIdx.x * 256 + threadIdx.x;
  if (i < EE * CAP) slot_tok[i] = 0;   // unfilled slots -> token 0 (rows masked)
  if (i < EE) cnt[i] = 0;
}

// ---------------- zero d_out --------------------------------------------
__global__ __launch_bounds__(256) void k_zero(float* __restrict__ out) {
  int i = blockIdx.x * 256 + threadIdx.x;
  ((float4*)out)[i] = (float4){0.f, 0.f, 0.f, 0.f};
}

// ---------------- f32 -> f16 cast ---------------------------------------
__global__ __launch_bounds__(256) void k_cast(const float* __restrict__ in,
                                              _Float16* __restrict__ out) {
  int i = blockIdx.x * 256 + threadIdx.x;
  float4 v = ((const float4*)in)[i];
  half4v h = { (_Float16)v.x, (_Float16)v.y, (_Float16)v.z, (_Float16)v.w };
  ((half4v*)out)[i] = h;
}

// ---------------- router: logits, top8, renorm, dispatch --------------------
__global__ __launch_bounds__(64) void k_router(
    const float* __restrict__ x, const float* __restrict__ rw,
    const float* __restrict__ wshg,
    float* __restrict__ shg, int* __restrict__ cnt,
    int* __restrict__ slot_tok, float* __restrict__ slot_w) {
  int t = blockIdx.x;
  int lane = threadIdx.x;
  const float* xr = x + (size_t)t * DD;
  float xv[32];
#pragma unroll
  for (int j = 0; j < 32; ++j) xv[j] = xr[lane + j * 64];

  __shared__ float lg[EE];
  for (int e = 0; e < EE; ++e) {
    const float* we = rw + (size_t)e * DD;
    float s = 0.f;
#pragma unroll
    for (int j = 0; j < 32; ++j) s += xv[j] * we[lane + j * 64];
#pragma unroll
    for (int off = 32; off > 0; off >>= 1) s += __shfl_down(s, off);
    if (lane == 0) lg[e] = s;
  }
  {
    float s = 0.f;
#pragma unroll
    for (int j = 0; j < 32; ++j) s += xv[j] * wshg[lane + j * 64];
#pragma unroll
    for (int off = 32; off > 0; off >>= 1) s += __shfl_down(s, off);
    if (lane == 0) shg[t] = 1.f / (1.f + expf(-s));
  }
  if (lane == 0) {
    unsigned used = 0;
    int sel[KTOP];
    float val[KTOP];
    for (int k = 0; k < KTOP; ++k) {
      float bv = -1e30f; int bi = 0;
      for (int e = 0; e < EE; ++e)
        if (!((used >> e) & 1) && lg[e] > bv) { bv = lg[e]; bi = e; }
      used |= (1u << bi);
      sel[k] = bi; val[k] = bv;
    }
    float mx = val[0], sum = 0.f;
    for (int k = 0; k < KTOP; ++k) { val[k] = expf(val[k] - mx); sum += val[k]; }
    float inv = 1.f / sum;
    for (int k = 0; k < KTOP; ++k) {
      int e = sel[k];
      int pos = atomicAdd(&cnt[e], 1);
      if (pos < CAP) {
        slot_tok[e * CAP + pos] = t;
        slot_w[e * CAP + pos] = val[k] * inv;
      }
    }
  }
}

// ---------------- grouped GEMM: C = A (rows x K, f16) * B (N x K, f32)^T ----
// Pipeline: sA[3] via global_load_lds (pre-swizzled source), sB[2] reg-staged
// with fused dequant; 1 raw s_barrier per K-tile; counted vmcnt(12).
// Template: DUAL (gate+up + SwiGLU), GATHER (A rows via slot_tok), DEQ
// (128x128 block scales), EPI (0=f16 out, 1=atomic scatter, 2=out+=shg*val),
// NPB (n-panels), MBB (m-blocks), KDIM (reduction length).
template<bool DUAL, bool GATHER, bool DEQ, int EPI, int NPB, int MBB, int KDIM>
__global__ __launch_bounds__(256, 2) void k_gemm(
    const _Float16* __restrict__ A,
    const float* __restrict__ B0f, const float* __restrict__ B1f,
    const float* __restrict__ S0, const float* __restrict__ S1,
    int sCols, int sStrideE,
    _Float16* __restrict__ OutH, float* __restrict__ OutF,
    const float* __restrict__ shg,
    int ldA, int ldOut,
    long long strideAE, long long strideBE, long long strideOE,
    const int* __restrict__ cnt, int rowsConst,
    const int* __restrict__ slot_tok, const float* __restrict__ slot_w) {
  constexpr int BK = 64;
  constexpr int KT = KDIM / BK;              // 32 / 12 / 32 / 32 (all even)
  constexpr int NF = DUAL ? 2 : 4;
  constexpr int BN = DUAL ? 64 : 128;
  constexpr int BCH = DUAL ? 4 : 8;          // float4 staging chunks / thread / op

  // ---- bijective XCD swizzle: all m-blocks of pair (n,e) on one XCD ----
  const int f = blockIdx.x;
  const int xcd = f & 7;
  const int t0 = f >> 3;
  const int mb = t0 % MBB;
  const int pp = t0 / MBB;
  const int p  = pp * 8 + xcd;               // pair id; (NPB*E) % 8 == 0
  const int nb = p % NPB;
  const int e  = p / NPB;

  int rows = cnt ? (cnt[e] > CAP ? CAP : cnt[e]) : rowsConst;
  const int rowBase = mb * 128;
  if (rowBase >= rows) return;
  const int nBase = nb * BN;

  const int tid = threadIdx.x;
  const int lane = tid & 63;
  const int wave = tid >> 6;
  const int wr = wave >> 1;
  const int wc = wave & 1;

  __shared__ __align__(16) _Float16 sA[3][8192];   // 48 KB (128 x 64 f16 each)
  __shared__ __align__(16) _Float16 sB[2][8192];   // 32 KB

  const _Float16* Ae = A + (GATHER ? 0 : (long long)e * strideAE);
  const float* B0e = B0f + (long long)e * strideBE;
  const float* B1e = DUAL ? (B1f + (long long)e * strideBE) : nullptr;
  const float* S0e = DEQ ? (S0 + (long long)e * sStrideE) : nullptr;
  const float* S1e = (DEQ && DUAL) ? (S1 + (long long)e * sStrideE) : nullptr;
  const int sRow = DEQ ? (nBase >> 7) * sCols : 0;

  // A staging (global_load_lds): LDS dest linear, source col pre-swizzled.
  long long aByte[4];
#pragma unroll
  for (int i = 0; i < 4; ++i) {
    int c = tid + i * 256;                   // 16B chunk id [0,1024)
    int row = c >> 3;                        // tile row 0..127
    int colB = ((c & 7) << 4) ^ ((row & 7) << 4);   // swizzled col byte [0,128)
    int src = GATHER ? slot_tok[e * CAP + rowBase + row] : (rowBase + row);
    aByte[i] = (long long)src * (2LL * ldA) + colB;
  }
  // B staging: reg->cvt->swizzled LDS write (row-uniform per 16 lanes: no WR conflict)
  long long bOff[BCH];
  int wByte[BCH];
#pragma unroll
  for (int i = 0; i < BCH; ++i) {
    int c = tid + i * 256;
    int rn = c >> 4;                         // B row in panel
    int c4 = (c & 15) << 2;                  // f32 col 0..60 step 4
    bOff[i] = (long long)(nBase + rn) * KDIM + c4;
    wByte[i] = ((rn << 7) + (c4 << 1)) ^ ((rn & 7) << 4);
  }

  f32x4 accG[4][NF];
  f32x4 accU[DUAL ? 4 : 1][NF];
#pragma unroll
  for (int m = 0; m < 4; ++m)
#pragma unroll
    for (int n = 0; n < NF; ++n) {
      accG[m][n] = (f32x4){0.f, 0.f, 0.f, 0.f};
      if constexpr (DUAL) accU[m][n] = (f32x4){0.f, 0.f, 0.f, 0.f};
    }

  auto stageA = [&](int kt, int buf) {       // 4 DMA ops
#pragma unroll
    for (int i = 0; i < 4; ++i) {
      __builtin_amdgcn_global_load_lds(
          (const __attribute__((address_space(1))) void*)
              ((const char*)Ae + aByte[i] + kt * (BK * 2)),
          (__attribute__((address_space(3))) void*)&sA[buf][(size_t)(tid + i * 256) * 8],
          16, 0, 0);
    }
  };
  auto loadB = [&](int kt, float4 (&r0)[BCH], float4 (&r1)[BCH]) {  // 8 loads
    const int ko = kt * BK;
#pragma unroll
    for (int i = 0; i < BCH; ++i) r0[i] = *(const float4*)(B0e + bOff[i] + ko);
    if constexpr (DUAL) {
#pragma unroll
      for (int i = 0; i < BCH; ++i) r1[i] = *(const float4*)(B1e + bOff[i] + ko);
    }
  };
  auto storeB = [&](int kt, float4 (&r0)[BCH], float4 (&r1)[BCH]) {
    float s0 = 1.f, s1 = 1.f;
    if constexpr (DEQ) {
      s0 = S0e[sRow + (kt >> 1)];
      if constexpr (DUAL) s1 = S1e[sRow + (kt >> 1)];
    }
    char* base = (char*)&sB[kt & 1][0];
#pragma unroll
    for (int i = 0; i < BCH; ++i) {
      half4v h = { (_Float16)(r0[i].x * s0), (_Float16)(r0[i].y * s0),
                   (_Float16)(r0[i].z * s0), (_Float16)(r0[i].w * s0) };
      *(half4v*)(base + wByte[i]) = h;
      if constexpr (DUAL) {
        half4v h1 = { (_Float16)(r1[i].x * s1), (_Float16)(r1[i].y * s1),
                      (_Float16)(r1[i].z * s1), (_Float16)(r1[i].w * s1) };
        *(half4v*)(base + 8192 + wByte[i]) = h1;
      }
    }
  };
  auto computeTile = [&](int ia, int ib) {
    const char* pA = (const char*)&sA[ia][0];
    const char* pB = (const char*)&sB[ib][0];
#pragma unroll
    for (int kk = 0; kk < 2; ++kk) {
      const int koff = kk * 32 + (lane >> 4) * 8;    // f16 elems
      half8 a[4];
#pragma unroll
      for (int m = 0; m < 4; ++m) {
        int r = wr * 64 + m * 16 + (lane & 15);
        int byt = ((r << 7) + (koff << 1)) ^ ((r & 7) << 4);
        a[m] = *(const half8*)(pA + byt);
      }
      if constexpr (DUAL) {
        half8 bg[2], bu[2];
#pragma unroll
        for (int n = 0; n < 2; ++n) {
          int rn = wc * 32 + n * 16 + (lane & 15);
          int byt = ((rn << 7) + (koff << 1)) ^ ((rn & 7) << 4);
          bg[n] = *(const half8*)(pB + byt);
          bu[n] = *(const half8*)(pB + 8192 + byt);
        }
#pragma unroll
        for (int m = 0; m < 4; ++m)
#pragma unroll
          for (int n = 0; n < 2; ++n) {
            accG[m][n] = __builtin_amdgcn_mfma_f32_16x16x32_f16(a[m], bg[n], accG[m][n], 0, 0, 0);
            accU[m][n] = __builtin_amdgcn_mfma_f32_16x16x32_f16(a[m], bu[n], accU[m][n], 0, 0, 0);
          }
      } else {
        half8 b[4];
#pragma unroll
        for (int n = 0; n < 4; ++n) {
          int rn = wc * 64 + n * 16 + (lane & 15);
          int byt = ((rn << 7) + (koff << 1)) ^ ((rn & 7) << 4);
          b[n] = *(const half8*)(pB + byt);
        }
#pragma unroll
        for (int m = 0; m < 4; ++m)
#pragma unroll
          for (int n = 0; n < 4; ++n)
            accG[m][n] = __builtin_amdgcn_mfma_f32_16x16x32_f16(a[m], b[n], accG[m][n], 0, 0, 0);
      }
    }
  };

  // even/odd named register sets (no runtime-indexed reg arrays -> no scratch)
  float4 rbE0[BCH], rbE1[BCH], rbO0[BCH], rbO1[BCH];

  // prologue: tiles 0 and 1 in flight (12 ops each; keep issue groups ordered)
  stageA(0, 0); loadB(0, rbE0, rbE1);
  __builtin_amdgcn_sched_barrier(0);
  stageA(1, 1); loadB(1, rbO0, rbO1);
  __builtin_amdgcn_sched_barrier(0);

  int bufC = 0;   // sA buffer of current tile
  int bufW = 2;   // sA buffer for next issued tile

  for (int kt = 0; kt < KT; kt += 2) {
    // ---------- even tile kt ----------
    if (kt + 1 < KT) { asm volatile("s_waitcnt vmcnt(12)" ::: "memory"); }
    else             { asm volatile("s_waitcnt vmcnt(0)"  ::: "memory"); }
    __builtin_amdgcn_sched_barrier(0);
    storeB(kt, rbE0, rbE1);
    asm volatile("s_waitcnt lgkmcnt(0)" ::: "memory");
    __builtin_amdgcn_sched_barrier(0);
    __builtin_amdgcn_s_barrier();
    __builtin_amdgcn_sched_barrier(0);
    if (kt + 2 < KT) { stageA(kt + 2, bufW); loadB(kt + 2, rbE0, rbE1); }
    __builtin_amdgcn_sched_barrier(0);
    computeTile(bufC, 0);
    bufC = (bufC == 2) ? 0 : bufC + 1;
    bufW = (bufW == 2) ? 0 : bufW + 1;

    // ---------- odd tile kt+1 ----------
    if (kt + 2 < KT) { asm volatile("s_waitcnt vmcnt(12)" ::: "memory"); }
    else             { asm volatile("s_waitcnt vmcnt(0)"  ::: "memory"); }
    __builtin_amdgcn_sched_barrier(0);
    storeB(kt + 1, rbO0, rbO1);
    asm volatile("s_waitcnt lgkmcnt(0)" ::: "memory");
    __builtin_amdgcn_sched_barrier(0);
    __builtin_amdgcn_s_barrier();
    __builtin_amdgcn_sched_barrier(0);
    if (kt + 3 < KT) { stageA(kt + 3, bufW); loadB(kt + 3, rbO0, rbO1); }
    __builtin_amdgcn_sched_barrier(0);
    computeTile(bufC, 1);
    bufC = (bufC == 2) ? 0 : bufC + 1;
    bufW = (bufW == 2) ? 0 : bufW + 1;
  }

  // epilogue; C/D layout: col = lane&15, row = (lane>>4)*4 + i (verified r1/r2)
#pragma unroll
  for (int m = 0; m < 4; ++m) {
#pragma unroll
    for (int i = 0; i < 4; ++i) {
      int row = rowBase + wr * 64 + m * 16 + (lane >> 4) * 4 + i;
      if (row < rows) {
        if constexpr (EPI == 1) {
          int tok = slot_tok[e * CAP + row];
          float w = slot_w[e * CAP + row];
#pragma unroll
          for (int n = 0; n < NF; ++n) {
            int col = nBase + wc * 64 + n * 16 + (lane & 15);
            unsafeAtomicAdd(&OutF[(long long)tok * DD + col], w * accG[m][n][i]);
          }
        } else if constexpr (EPI == 2) {
          float g = shg[row];
#pragma unroll
          for (int n = 0; n < NF; ++n) {
            int col = nBase + wc * 64 + n * 16 + (lane & 15);
            long long o = (long long)row * DD + col;
            OutF[o] += g * accG[m][n][i];
          }
        } else {
          long long outBase = (long long)e * strideOE;
#pragma unroll
          for (int n = 0; n < NF; ++n) {
            int col = nBase + (DUAL ? wc * 32 : wc * 64) + n * 16 + (lane & 15);
            long long o = outBase + (long long)row * ldOut + col;
            if constexpr (DUAL) {
              float gv = accG[m][n][i];
              float uv = accU[m][n][i];
              OutH[o] = (_Float16)((gv / (1.f + __expf(-gv))) * uv);
            } else {
              OutH[o] = (_Float16)accG[m][n][i];
            }
          }
        }
      }
    }
  }
}

// ---------------------------------------------------------------------------
extern "C" void kernel_launch(void* const* d_in, const int* in_sizes, int n_in,
                              void* d_out, int out_size, void* d_ws, size_t ws_size,
                              hipStream_t stream) {
  (void)in_sizes; (void)n_in; (void)out_size; (void)ws_size;
  const float* x    = (const float*)d_in[0];
  const float* rw   = (const float*)d_in[1];
  const float* wg   = (const float*)d_in[2];
  const float* sg   = (const float*)d_in[3];
  const float* wu   = (const float*)d_in[4];
  const float* su   = (const float*)d_in[5];
  const float* wd   = (const float*)d_in[6];
  const float* sd   = (const float*)d_in[7];
  const float* wsg  = (const float*)d_in[8];
  const float* wsu  = (const float*)d_in[9];
  const float* wsd  = (const float*)d_in[10];
  const float* wshg = (const float*)d_in[11];
  float* out = (float*)d_out;

  // workspace (~67.4 MB)
  char* p = (char*)d_ws;
  auto alloc = [&](size_t bytes) {
    char* r = p;
    p += (bytes + 255) & ~(size_t)255;
    return r;
  };
  _Float16* x_h = (_Float16*)alloc((size_t)TT * DD * 2);
  _Float16* H   = (_Float16*)alloc((size_t)EE * CAP * DFF * 2);
  _Float16* Hsh = (_Float16*)alloc((size_t)TT * DSH * 2);
  float* shg    = (float*)alloc((size_t)TT * 4);
  int* cnt      = (int*)alloc((size_t)EE * 4);
  int* slot_tok = (int*)alloc((size_t)EE * CAP * 4);
  float* slot_w = (float*)alloc((size_t)EE * CAP * 4);

  k_init<<<(EE * CAP + 255) / 256, 256, 0, stream>>>(cnt, slot_tok);
  k_zero<<<(TT * DD / 4) / 256, 256, 0, stream>>>(out);
  k_cast<<<(TT * DD / 4) / 256, 256, 0, stream>>>(x, x_h);
  k_router<<<TT, 64, 0, stream>>>(x, rw, wshg, shg, cnt, slot_tok, slot_w);

  // routed gate+up: NP=12, MB=8, E=32 -> 3072 flat blocks
  k_gemm<true, true, true, 0, 12, 8, DD><<<3072, 256, 0, stream>>>(
      x_h, wg, wu, sg, su, DD / 128, (DFF / 128) * (DD / 128),
      H, nullptr, nullptr,
      DD, DFF,
      0LL, (long long)DFF * DD, (long long)CAP * DFF,
      cnt, 0, slot_tok, nullptr);

  // routed down + weighted atomic scatter: NP=16, MB=8, E=32 -> 4096 blocks
  k_gemm<false, false, true, 1, 16, 8, DFF><<<4096, 256, 0, stream>>>(
      H, wd, wd, sd, sd, DFF / 128, (DD / 128) * (DFF / 128),
      nullptr, out, nullptr,
      DFF, DD,
      (long long)CAP * DFF, (long long)DD * DFF, 0LL,
      cnt, 0, slot_tok, slot_w);

  // shared gate+up: NP=32, MB=16, E=1 -> 512 blocks
  k_gemm<true, false, false, 0, 32, 16, DD><<<512, 256, 0, stream>>>(
      x_h, wsg, wsu, nullptr, nullptr, 0, 0,
      Hsh, nullptr, nullptr,
      DD, DSH,
      0LL, 0LL, 0LL,
      nullptr, TT, nullptr, nullptr);

  // shared down (out += shg*val, runs last): NP=16, MB=16, E=1 -> 256 blocks
  k_gemm<false, false, false, 2, 16, 16, DSH><<<256, 256, 0, stream>>>(
      Hsh, wsd, wsd, nullptr, nullptr, 0, 0,
      nullptr, out, shg,
      DSH, DD,
      0LL, 0LL, 0LL,
      nullptr, TT, nullptr, nullptr);
}